// Round 1
// baseline (76.928 us; speedup 1.0000x reference)
//
#include <hip/hip_runtime.h>

#define BB 32
#define RR 56
#define CC 56
#define CHN 256

// One wave (64 lanes) per output pixel; lane l handles channels [4l, 4l+4) as float4.
// out = x + sum over 8 neighbors (center tap masked to 0) of k[dr][dc][ch] * x[nbr].
__global__ __launch_bounds__(256) void dwconv3x3_residual(
    const float* __restrict__ x,
    const float* __restrict__ kern,
    float* __restrict__ out)
{
    const int tid  = blockIdx.x * 256 + threadIdx.x;
    const int pix  = tid >> 6;          // (b*R + r)*C + c
    const int lane = tid & 63;          // channel group
    if (pix >= BB * RR * CC) return;

    const int b  = pix / (RR * CC);
    const int rc = pix - b * (RR * CC);
    const int r  = rc / CC;
    const int c  = rc - r * CC;

    const float4* __restrict__ xv = (const float4*)x;
    const float4* __restrict__ kv = (const float4*)kern;
    float4* __restrict__ ov = (float4*)out;

    // index in float4 units: pixel*64 + lane
    const int base4 = pix * (CHN / 4) + lane;

    float4 acc = xv[base4];   // residual (center tap is zero)

    const bool interior = (r > 0) & (r < RR - 1) & (c > 0) & (c < CC - 1);

    if (interior) {
        #pragma unroll
        for (int dr = -1; dr <= 1; ++dr) {
            #pragma unroll
            for (int dc = -1; dc <= 1; ++dc) {
                if (dr == 0 && dc == 0) continue;
                const float4 xn = xv[base4 + (dr * CC + dc) * (CHN / 4)];
                const float4 kt = kv[((dr + 1) * 3 + (dc + 1)) * (CHN / 4) + lane];
                acc.x += kt.x * xn.x;
                acc.y += kt.y * xn.y;
                acc.z += kt.z * xn.z;
                acc.w += kt.w * xn.w;
            }
        }
    } else {
        #pragma unroll
        for (int dr = -1; dr <= 1; ++dr) {
            #pragma unroll
            for (int dc = -1; dc <= 1; ++dc) {
                if (dr == 0 && dc == 0) continue;
                const int rr2 = r + dr, cc2 = c + dc;
                if (rr2 < 0 || rr2 >= RR || cc2 < 0 || cc2 >= CC) continue;
                const float4 xn = xv[base4 + (dr * CC + dc) * (CHN / 4)];
                const float4 kt = kv[((dr + 1) * 3 + (dc + 1)) * (CHN / 4) + lane];
                acc.x += kt.x * xn.x;
                acc.y += kt.y * xn.y;
                acc.z += kt.z * xn.z;
                acc.w += kt.w * xn.w;
            }
        }
    }

    ov[base4] = acc;
}

extern "C" void kernel_launch(void* const* d_in, const int* in_sizes, int n_in,
                              void* d_out, int out_size, void* d_ws, size_t ws_size,
                              hipStream_t stream)
{
    const float* x    = (const float*)d_in[0];
    const float* kern = (const float*)d_in[1];
    float* out        = (float*)d_out;

    const int total_threads = BB * RR * CC * (CHN / 4);  // 64 threads per pixel
    const int blocks = (total_threads + 255) / 256;      // 25088

    dwconv3x3_residual<<<blocks, 256, 0, stream>>>(x, kern, out);
}

// Round 2
// 35.727 us; speedup vs baseline: 2.1532x; 2.1532x over previous
//
#include <hip/hip_runtime.h>

#define BB 32
#define RR 56
#define CC 56
#define CHG 64                      // channel float4-groups (256/4)
#define TP 4                        // output pixels per thread (along C)
#define SEGS (BB * RR * (CC / TP))  // 25088 wave-segments
#define NBLK (SEGS / 4)             // 6272 blocks (4 waves each), % 8 == 0

// One wave per 4-pixel row segment; lane = channel group. Each thread loads a
// 3x6 float4 neighborhood once and produces 4 outputs from registers.
__global__ __launch_bounds__(256) void dwconv3x3_residual2(
    const float4* __restrict__ xv,
    const float4* __restrict__ kv,
    float4* __restrict__ ov)
{
    // XCD-aware chunked swizzle: XCD i gets segments [i*SEGS/8, (i+1)*SEGS/8)
    // = exactly 4 contiguous batch images -> all stencil reuse stays in one L2.
    const int bid = (int)blockIdx.x;
    const int swz = (bid & 7) * (NBLK / 8) + (bid >> 3);
    const int tid = swz * 256 + (int)threadIdx.x;
    const int seg = tid >> 6;
    const int lane = tid & 63;

    const int b   = seg / (RR * (CC / TP));
    const int rem = seg - b * (RR * (CC / TP));
    const int r   = rem / (CC / TP);
    const int cs  = rem - r * (CC / TP);
    const int c0  = cs * TP;

    // kernel taps: 3x3 x float4; center (t=4) unused (masked in reference)
    float4 kt[9];
    #pragma unroll
    for (int t = 0; t < 9; ++t)
        kt[t] = kv[t * CHG + lane];

    float4 row[3][TP + 2];
    const int pixbase = (b * RR + r) * CC + c0;

    const bool interior = (r > 0) & (r < RR - 1) & (cs > 0) & (cs < (CC / TP) - 1);
    if (interior) {
        // branch is wave-uniform (r, cs identical across lanes)
        #pragma unroll
        for (int dr = 0; dr < 3; ++dr) {
            const int rowbase = (pixbase + (dr - 1) * CC - 1) * CHG + lane;
            #pragma unroll
            for (int j = 0; j < TP + 2; ++j)
                row[dr][j] = xv[rowbase + j * CHG];
        }
    } else {
        #pragma unroll
        for (int dr = 0; dr < 3; ++dr) {
            const int rr2 = r + dr - 1;
            #pragma unroll
            for (int j = 0; j < TP + 2; ++j) {
                const int cc2 = c0 + j - 1;
                float4 v = make_float4(0.f, 0.f, 0.f, 0.f);
                if (rr2 >= 0 && rr2 < RR && cc2 >= 0 && cc2 < CC)
                    v = xv[((b * RR + rr2) * CC + cc2) * CHG + lane];
                row[dr][j] = v;
            }
        }
    }

    #pragma unroll
    for (int p = 0; p < TP; ++p) {
        float4 acc = row[1][p + 1];   // residual (center tap zeroed)
        #pragma unroll
        for (int dr = 0; dr < 3; ++dr) {
            #pragma unroll
            for (int dc = 0; dc < 3; ++dc) {
                if (dr == 1 && dc == 1) continue;
                const float4 kk = kt[dr * 3 + dc];
                const float4 xx = row[dr][p + dc];
                acc.x += kk.x * xx.x;
                acc.y += kk.y * xx.y;
                acc.z += kk.z * xx.z;
                acc.w += kk.w * xx.w;
            }
        }
        ov[(pixbase + p) * CHG + lane] = acc;
    }
}

extern "C" void kernel_launch(void* const* d_in, const int* in_sizes, int n_in,
                              void* d_out, int out_size, void* d_ws, size_t ws_size,
                              hipStream_t stream)
{
    const float4* xv = (const float4*)d_in[0];
    const float4* kv = (const float4*)d_in[1];
    float4* ov       = (float4*)d_out;

    dwconv3x3_residual2<<<NBLK, 256, 0, stream>>>(xv, kv, ov);
}